// Round 5
// baseline (260.682 us; speedup 1.0000x reference)
//
#include <hip/hip_runtime.h>
#include <cstdint>

#define A_NUM 9
#define C_NUM 20
#define B_SZ 32
#define HW 784            // 28*28
#define P_NUM (A_NUM*HW)  // 7056
#define NBOX 64
#define CIN 1280
#define HID 128
#define M_IDX 4096
#define KS_HALF 20        // k-steps per wave (K-split 2: 2*20*32 = 1280)
#define HSTR2 136         // h LDS row stride in bf16 elems (272 B, 16B-aligned)
#define OSTR 80           // Hd row stride in floats (65 used, pad to 80)
#define IOU_PB 64         // p-rows per iou block

// output layout (flat concat in return order)
#define CONF_OFF 0
#define OFFS_OFF (2*M_IDX)                 // 8192
#define CLS_OFF  (OFFS_OFF + 4*M_IDX)      // 24576
#define IOU_OFF  (CLS_OFF + C_NUM*M_IDX)   // 106496

// fused-kernel grid: IoU blocks FIRST (drain write burst), then GEMM blocks.
#define IOU_BX ((P_NUM + IOU_PB - 1)/IOU_PB)      // 111
#define IOU_BLKS (IOU_BX*B_SZ)                    // 3552
#define GEMM_MT 25                                // 32-row m-tiles (800 >= 784)
#define GEMM_BLKS (GEMM_MT*B_SZ)                  // 800

typedef short bf16x8 __attribute__((ext_vector_type(8)));
typedef float f32x4  __attribute__((ext_vector_type(4)));

// round-half-up fp32->bf16, packed pair into one dword
__device__ __forceinline__ unsigned pack_bf16(float lo, float hi) {
  unsigned a = __builtin_bit_cast(unsigned, lo);
  unsigned b = __builtin_bit_cast(unsigned, hi);
  return ((a + 0x8000u) >> 16) | ((b + 0x8000u) & 0xffff0000u);
}

// ---- weight prep: W1 and W2 fp32 -> bf16 MFMA B-fragment order -------------
// W1f layout: [ks(40)][ntile(8)][lane(64)][k8], lane=(quad,lo): n=ntile*16+lo,
// k = ks*32 + quad*8 + j.
// W2f layout: [ks(4)][ntile(5)][lane(64)][k8], n(=o)=ntile*16+lo (o>=65 -> 0).
__global__ __launch_bounds__(256) void prep_w(const float* __restrict__ W1,
                                              const float* __restrict__ W2,
                                              uint4* __restrict__ W1f,
                                              uint4* __restrict__ W2f) {
  int id = blockIdx.x * 256 + threadIdx.x;  // 85*256 = 21760 threads
  if (id < 20480) {
    int lane = id & 63;
    int ntile = (id >> 6) & 7;
    int ks = id >> 9;                       // 0..39
    int lo = lane & 15, quad = lane >> 4;
    int n = ntile * 16 + lo;
    int k0 = ks * 32 + quad * 8;
    const float* src = W1 + n * CIN + k0;
    float4 x = *(const float4*)src;
    float4 y = *(const float4*)(src + 4);
    uint4 p;
    p.x = pack_bf16(x.x, x.y);
    p.y = pack_bf16(x.z, x.w);
    p.z = pack_bf16(y.x, y.y);
    p.w = pack_bf16(y.z, y.w);
    W1f[id] = p;
  } else {
    int i2 = id - 20480;                    // 0..1279
    int lane = i2 & 63;
    int ntile = (i2 >> 6) % 5;
    int ks = i2 / 320;                      // 0..3
    int lo = lane & 15, quad = lane >> 4;
    int n = ntile * 16 + lo;
    int k0 = ks * 32 + quad * 8;
    uint4 p = (uint4){0, 0, 0, 0};
    if (n < 5 * A_NUM + C_NUM) {
      const float* src = W2 + n * HID + k0;
      float4 x = *(const float4*)src;
      float4 y = *(const float4*)(src + 4);
      p.x = pack_bf16(x.x, x.y);
      p.y = pack_bf16(x.z, x.w);
      p.z = pack_bf16(y.x, y.y);
      p.w = pack_bf16(y.z, y.w);
    }
    W2f[i2] = p;
  }
}

// ---- fused: coalesced-A GEMM (K-split-2 x N-split-2) + head + IoU ----------
// A path: global float4 (128 B segs) -> reg 4x4 transpose -> bf16 -> per-wave
// private swizzled LDS frag buffer (no barriers) -> ds_read_b128 fragments.
union SharedU {
  struct {
    unsigned short stage[4][2][1024];    // [wave][buf] frag tile, 2 KB each = 16 KB
    f32x4 stash[2][2][4][64];            // [nh][mf][nf][lane] K-reduce, 16 KB
    unsigned short h[32 * HSTR2];        // bf16 h tile [32][128] padded, 8704 B
  } g;                                   // total 41472 B
  struct { float sb[NBOX * 5]; float4 sp4[IOU_PB]; } i;  // 2304 B (iou)
};

__global__ __launch_bounds__(256) void fused_main(
    const float* __restrict__ F, const uint4* __restrict__ W1f,
    const uint4* __restrict__ W2f, const float* __restrict__ b1,
    const float* __restrict__ b2, float* __restrict__ Hd,
    const float* __restrict__ gridc, const float* __restrict__ anc,
    const float* __restrict__ bboxes, float* __restrict__ iou_out) {
  __shared__ SharedU sh;
  const int bid = blockIdx.x;
  const int t = threadIdx.x;

  if (bid < IOU_BLKS) {
    // ================= IoU part (unchanged math) =================
    const int b = bid / IOU_BX;
    const int p0 = (bid - b * IOU_BX) * IOU_PB;
    float* sb = sh.i.sb;
    float4* sp4 = sh.i.sp4;
    for (int i = t; i < NBOX * 5; i += 256) sb[i] = bboxes[b * NBOX * 5 + i];
    if (t < IOU_PB) {
      int p = p0 + t;
      float x1 = 0.f, y1 = 0.f, x2 = 0.f, y2 = 0.f;
      if (p < P_NUM) {
        int a = p / HW, hw = p - a * HW;
        float2 c = ((const float2*)gridc)[b * HW + hw];
        float hx = anc[a * 2 + 0] * 0.5f, hy = anc[a * 2 + 1] * 0.5f;
        x1 = c.x - hx; y1 = c.y - hy; x2 = c.x + hx; y2 = c.y + hy;
      }
      sp4[t] = make_float4(x1, y1, x2, y2);
    }
    __syncthreads();
    const int nl = (t & 15) * 4;
    const int pi = t >> 4;
#pragma unroll
    for (int ip = 0; ip < 4; ip++) {
      const int pl = pi + 16 * ip;
      const int p = p0 + pl;
      const float4 pb = sp4[pl];
      const float spA = (pb.z - pb.x) * (pb.w - pb.y);
      float4 res;
#pragma unroll
      for (int jn = 0; jn < 4; jn++) {
        const int n = nl + jn;
        float bx1 = sb[n * 5 + 0], by1 = sb[n * 5 + 1];
        float bx2 = sb[n * 5 + 2], by2 = sb[n * 5 + 3];
        float s_b = (bx2 - bx1) * (by2 - by1);
        float ix1 = fmaxf(pb.x, bx1), iy1 = fmaxf(pb.y, by1);
        float ix2 = fminf(pb.z, bx2), iy2 = fminf(pb.w, by2);
        float si = fmaxf(ix2 - ix1, 0.f) * fmaxf(iy2 - iy1, 0.f);
        float su = spA + s_b - si;
        float iou = fmaxf(si / (su + 1e-8f), 0.f);
        bool invalid = (su <= 0.f) | (spA <= 0.f) | (s_b <= 0.f) | (bx1 < 0.f);
        float v = invalid ? 0.f : iou;
        if (jn == 0) res.x = v; else if (jn == 1) res.y = v;
        else if (jn == 2) res.z = v; else res.w = v;
      }
      if (p < P_NUM)
        *(float4*)&iou_out[((size_t)(b * P_NUM + p)) * 64 + nl] = res;
    }
    return;
  }

  // ===== GEMM: 32m x 128n tile; wave(ks=w>>1, nh=w&1): k-half, n-half =======
  const int gid = bid - IOU_BLKS;
  const int w = t >> 6, lane = t & 63;
  const int quad = lane >> 4, lo = lane & 15;
  const int ks = w >> 1, nh = w & 1;
  const int b = gid / GEMM_MT;
  const int mt = gid - b * GEMM_MT;
  const int m0 = mt * 32;

  // A loader lane role: kq = lane>>3 covers k-rows kq*4..+3; ml = (lane&7)*4
  const int kq = lane >> 3;
  const int ml = (lane & 7) * 4;
  const int mld = min(m0 + ml, HW - 4);     // clamp: dup rows, outputs guarded
  const float* Fb = F + (size_t)b * CIN * HW + mld + (size_t)(ks * 640 + kq * 4) * HW;
  const int j0 = (kq & 1) * 4;              // j-offset within frag quad

  f32x4 acc[2][4];
#pragma unroll
  for (int i = 0; i < 2; i++)
#pragma unroll
    for (int j = 0; j < 4; j++) acc[i][j] = (f32x4){0.f, 0.f, 0.f, 0.f};

  f32x4 ar0[4], ar1[4], ar2[4];   // A reg prefetch depth 3 (4x4 fp32 each)
  uint4 vb0[4], vb1[4];           // B frag prefetch depth 2

  auto loadA = [&](int kk, f32x4* ar) {
    const float* p = Fb + (size_t)kk * 32 * HW;
    ar[0] = *(const f32x4*)p;
    ar[1] = *(const f32x4*)(p + HW);
    ar[2] = *(const f32x4*)(p + 2 * HW);
    ar[3] = *(const f32x4*)(p + 3 * HW);
  };
  auto loadB = [&](int kk, uint4* vb) {
    const uint4* p = W1f + ((size_t)(ks * KS_HALF + kk) * 8 + nh * 4) * 64 + lane;
#pragma unroll
    for (int nf = 0; nf < 4; nf++) vb[nf] = p[nf * 64];
  };
  // reg 4x4 transpose + bf16 pack + swizzled frag write (per-wave private LDS)
  auto stageA = [&](int buf, f32x4* ar) {
    char* sg = (char*)sh.g.stage[w][buf];
#pragma unroll
    for (int dm = 0; dm < 4; dm++) {
      const int mloc = ml + dm;
      const int mf = mloc >> 4;
      const int lp = (lane >> 4) * 16 + (mloc & 15);   // frag lane' (k-quad, m&15)
      unsigned byte = mf * 1024 + lp * 16 + j0 * 2;
      byte ^= ((unsigned)(lp >> 4) & 3u) << 5;         // bank swizzle
      unsigned d0 = pack_bf16(ar[0][dm], ar[1][dm]);
      unsigned d1 = pack_bf16(ar[2][dm], ar[3][dm]);
      *(uint2*)(sg + byte) = (uint2){d0, d1};
    }
  };
  auto compute = [&](int buf, uint4* vb) {
    const char* sg = (const char*)sh.g.stage[w][buf];
    bf16x8 af[2];
#pragma unroll
    for (int mf = 0; mf < 2; mf++) {
      unsigned byte = mf * 1024 + lane * 16;
      byte ^= ((unsigned)(lane >> 4) & 3u) << 5;
      af[mf] = *(const bf16x8*)(sg + byte);
    }
#pragma unroll
    for (int mf = 0; mf < 2; mf++)
#pragma unroll
      for (int nf = 0; nf < 4; nf++)
        acc[mf][nf] = __builtin_amdgcn_mfma_f32_16x16x32_bf16(
            af[mf], __builtin_bit_cast(bf16x8, vb[nf]), acc[mf][nf], 0, 0, 0);
  };

  loadA(0, ar0); loadA(1, ar1); loadA(2, ar2);
  loadB(0, vb0); loadB(1, vb1);
  stageA(0, ar0);
#pragma unroll
  for (int kk = 0; kk < KS_HALF; kk++) {
    const int cur = kk & 1;
    compute(cur, cur ? vb1 : vb0);
    if (kk + 3 < KS_HALF) loadA(kk + 3, (kk % 3 == 0) ? ar0 : (kk % 3 == 1) ? ar1 : ar2);
    if (kk + 2 < KS_HALF) loadB(kk + 2, cur ? vb1 : vb0);
    if (kk + 1 < KS_HALF)
      stageA(cur ^ 1, ((kk + 1) % 3 == 0) ? ar0 : ((kk + 1) % 3 == 1) ? ar1 : ar2);
  }

  // ---- K-split reduce (one barrier): ks=1 stashes, ks=0 sums ---------------
  if (ks == 1) {
#pragma unroll
    for (int mf = 0; mf < 2; mf++)
#pragma unroll
      for (int nf = 0; nf < 4; nf++) sh.g.stash[nh][mf][nf][lane] = acc[mf][nf];
  }
  __syncthreads();
  if (ks == 0) {
#pragma unroll
    for (int mf = 0; mf < 2; mf++) {
#pragma unroll
      for (int nf = 0; nf < 4; nf++) {
        f32x4 s = acc[mf][nf] + sh.g.stash[nh][mf][nf][lane];
        const float bb = b1[nh * 64 + nf * 16 + lo];
#pragma unroll
        for (int r = 0; r < 4; r++) {
          float v = s[r] + bb;
          v = v > 0.f ? v : 0.01f * v;
          unsigned u = __builtin_bit_cast(unsigned, v);
          sh.g.h[(mf * 16 + quad * 4 + r) * HSTR2 + nh * 64 + nf * 16 + lo] =
              (unsigned short)((u + 0x8000u) >> 16);
        }
      }
    }
  }
  __syncthreads();

  // ---- W2 head: 10 units (mf,nt) split across 4 waves ----------------------
  for (int id = w; id < 10; id += 4) {
    const int mf = id / 5, nt = id - (id / 5) * 5;
    f32x4 acc2 = (f32x4){0.f, 0.f, 0.f, 0.f};
#pragma unroll
    for (int k2 = 0; k2 < 4; k2++) {
      bf16x8 haf = *(const bf16x8*)&sh.g.h[(mf * 16 + lo) * HSTR2 + k2 * 32 + quad * 8];
      bf16x8 bf = __builtin_bit_cast(bf16x8, W2f[(k2 * 5 + nt) * 64 + lane]);
      acc2 = __builtin_amdgcn_mfma_f32_16x16x32_bf16(haf, bf, acc2, 0, 0, 0);
    }
    const int o = nt * 16 + lo;
    if (o < 5 * A_NUM + C_NUM) {
      const float bz = b2[o];
      const int t5 = (o < 5 * A_NUM) ? (o % 5) : 5;
      const int mrow = m0 + mf * 16 + quad * 4;
#pragma unroll
      for (int r = 0; r < 4; r++) {
        const int m = mrow + r;
        if (m < HW) {
          float v = acc2[r] + bz;
          if (t5 == 0) v = 1.f / (1.f + expf(-v));
          else if (t5 == 1 || t5 == 2) v = 1.f / (1.f + expf(-v)) - 0.5f;
          Hd[((size_t)b * HW + m) * OSTR + o] = v;
        }
      }
    }
  }
}

// ---- gather: pure row copy from activated Hd -------------------------------
__global__ __launch_bounds__(256) void gather2(
    const int* __restrict__ pos_idx, const int* __restrict__ neg_idx,
    const float* __restrict__ Hd, float* __restrict__ out) {
  const int bid = blockIdx.x;
  if (bid < M_IDX / 8) {            // 512 blocks: 8 pos indices each
    const int g = threadIdx.x >> 5; // 32 lanes per index
    const int l = threadIdx.x & 31;
    const int slot = bid * 8 + g;
    const int idx = pos_idx[slot];
    const int b = idx / P_NUM, r = idx - b * P_NUM;
    const int a = r / HW, hw = r - a * HW;
    const float* row = Hd + ((size_t)b * HW + hw) * OSTR;
    if (l == 0)       out[CONF_OFF + slot] = row[a * 5];
    else if (l < 5)   out[OFFS_OFF + slot * 4 + (l - 1)] = row[a * 5 + l];
    else if (l < 25)  out[CLS_OFF + slot * C_NUM + (l - 5)] = row[5 * A_NUM + (l - 5)];
  } else {                          // 16 blocks: 1 neg index per thread
    const int tt = (bid - M_IDX / 8) * 256 + threadIdx.x;
    if (tt < M_IDX) {
      const int idx = neg_idx[tt];
      const int b = idx / P_NUM, r = idx - b * P_NUM;
      const int a = r / HW, hw = r - a * HW;
      out[CONF_OFF + M_IDX + tt] = Hd[((size_t)b * HW + hw) * OSTR + a * 5];
    }
  }
}

extern "C" void kernel_launch(void* const* d_in, const int* in_sizes, int n_in,
                              void* d_out, int out_size, void* d_ws, size_t ws_size,
                              hipStream_t stream) {
  const float* features = (const float*)d_in[0];
  const float* gridc    = (const float*)d_in[1];
  const float* anc      = (const float*)d_in[2];
  const float* bboxes   = (const float*)d_in[3];
  const int*   pos_idx  = (const int*)d_in[4];
  const int*   neg_idx  = (const int*)d_in[5];
  const float* W1       = (const float*)d_in[6];
  const float* b1       = (const float*)d_in[7];
  const float* W2       = (const float*)d_in[8];
  const float* b2       = (const float*)d_in[9];
  float* out = (float*)d_out;

  // ws: W1f (327680 B) | W2f (20480 B) | Hd (B*HW*OSTR fp32 = 8 MB)
  uint4* W1f = (uint4*)d_ws;
  uint4* W2f = (uint4*)((char*)d_ws + 327680);
  float* Hd  = (float*)((char*)d_ws + 327680 + 20480);

  hipLaunchKernelGGL(prep_w, dim3(85), dim3(256), 0, stream, W1, W2, W1f, W2f);
  hipLaunchKernelGGL(fused_main, dim3(IOU_BLKS + GEMM_BLKS), dim3(256), 0, stream,
                     features, W1f, W2f, b1, b2, Hd,
                     gridc, anc, bboxes, out + IOU_OFF);
  hipLaunchKernelGGL(gather2, dim3(M_IDX / 8 + 16), dim3(256), 0, stream,
                     pos_idx, neg_idx, Hd, out);
}

// Round 6
// 243.362 us; speedup vs baseline: 1.0712x; 1.0712x over previous
//
#include <hip/hip_runtime.h>
#include <cstdint>

#define A_NUM 9
#define C_NUM 20
#define B_SZ 32
#define HW 784            // 28*28
#define P_NUM (A_NUM*HW)  // 7056
#define NBOX 64
#define CIN 1280
#define HID 128
#define M_IDX 4096
#define KS_ALL 40         // 1280/32 k-steps
#define ASTR3 36          // As row stride in f32 (144 B, 16B-aligned, bank-spread)
#define HSTR2 136         // h LDS row stride in bf16 elems (272 B, 16B-aligned)
#define OSTR 80           // Hd row stride in floats (65 used, pad to 80)
#define IOU_PB 64         // p-rows per iou block

// output layout (flat concat in return order)
#define CONF_OFF 0
#define OFFS_OFF (2*M_IDX)                 // 8192
#define CLS_OFF  (OFFS_OFF + 4*M_IDX)      // 24576
#define IOU_OFF  (CLS_OFF + C_NUM*M_IDX)   // 106496

// fused grid: GEMM blocks first (r4 order), IoU appended
#define GEMM_MT 25                                // 32-row m-tiles (800 >= 784)
#define GEMM_BLKS (GEMM_MT*B_SZ)                  // 800
#define IOU_BX ((P_NUM + IOU_PB - 1)/IOU_PB)      // 111
#define IOU_BLKS (IOU_BX*B_SZ)                    // 3552

typedef short bf16x8 __attribute__((ext_vector_type(8)));
typedef float f32x4  __attribute__((ext_vector_type(4)));

// round-half-up fp32->bf16, packed pair into one dword
__device__ __forceinline__ unsigned pack_bf16(float lo, float hi) {
  unsigned a = __builtin_bit_cast(unsigned, lo);
  unsigned b = __builtin_bit_cast(unsigned, hi);
  return ((a + 0x8000u) >> 16) | ((b + 0x8000u) & 0xffff0000u);
}

// ---- weight prep: W1 and W2 fp32 -> bf16 MFMA B-fragment order -------------
// W1f layout: [ks(40)][ntile(8)][lane(64)][k8], lane=(quad,lo): n=ntile*16+lo,
// k = ks*32 + quad*8 + j.
// W2f layout: [ks(4)][ntile(5)][lane(64)][k8], n(=o)=ntile*16+lo (o>=65 -> 0).
__global__ __launch_bounds__(256) void prep_w(const float* __restrict__ W1,
                                              const float* __restrict__ W2,
                                              uint4* __restrict__ W1f,
                                              uint4* __restrict__ W2f) {
  int id = blockIdx.x * 256 + threadIdx.x;  // 85*256 = 21760 threads
  if (id < 20480) {
    int lane = id & 63;
    int ntile = (id >> 6) & 7;
    int ks = id >> 9;                       // 0..39
    int lo = lane & 15, quad = lane >> 4;
    int n = ntile * 16 + lo;
    int k0 = ks * 32 + quad * 8;
    const float* src = W1 + n * CIN + k0;
    float4 x = *(const float4*)src;
    float4 y = *(const float4*)(src + 4);
    uint4 p;
    p.x = pack_bf16(x.x, x.y);
    p.y = pack_bf16(x.z, x.w);
    p.z = pack_bf16(y.x, y.y);
    p.w = pack_bf16(y.z, y.w);
    W1f[id] = p;
  } else {
    int i2 = id - 20480;                    // 0..1279
    int lane = i2 & 63;
    int ntile = (i2 >> 6) % 5;
    int ks = i2 / 320;                      // 0..3
    int lo = lane & 15, quad = lane >> 4;
    int n = ntile * 16 + lo;
    int k0 = ks * 32 + quad * 8;
    uint4 p = (uint4){0, 0, 0, 0};
    if (n < 5 * A_NUM + C_NUM) {
      const float* src = W2 + n * HID + k0;
      float4 x = *(const float4*)src;
      float4 y = *(const float4*)(src + 4);
      p.x = pack_bf16(x.x, x.y);
      p.y = pack_bf16(x.z, x.w);
      p.z = pack_bf16(y.x, y.y);
      p.w = pack_bf16(y.z, y.w);
    }
    W2f[i2] = p;
  }
}

// ---- fused: block-coop dbuf GEMM (32m x 128n, n-split waves) + head + IoU --
union SharedU {
  struct {
    float As[2][32 * ASTR3];             // 9216 B: fp32 A tile [m32][k32+pad]
    unsigned short h[32 * HSTR2];        // 8704 B: bf16 h tile [32][128]
  } g;                                   // 17920 B total
  struct { float sb[NBOX * 5]; float4 sp4[IOU_PB]; } i;  // 2304 B (iou)
};

__global__ __launch_bounds__(256) void fused_main(
    const float* __restrict__ F, const uint4* __restrict__ W1f,
    const uint4* __restrict__ W2f, const float* __restrict__ b1,
    const float* __restrict__ b2, float* __restrict__ Hd,
    const float* __restrict__ gridc, const float* __restrict__ anc,
    const float* __restrict__ bboxes, float* __restrict__ iou_out) {
  __shared__ SharedU sh;
  const int bid = blockIdx.x;
  const int t = threadIdx.x;

  if (bid >= GEMM_BLKS) {
    // ================= IoU part (unchanged math) =================
    const int bid2 = bid - GEMM_BLKS;
    const int b = bid2 / IOU_BX;
    const int p0 = (bid2 - b * IOU_BX) * IOU_PB;
    float* sb = sh.i.sb;
    float4* sp4 = sh.i.sp4;
    for (int i = t; i < NBOX * 5; i += 256) sb[i] = bboxes[b * NBOX * 5 + i];
    if (t < IOU_PB) {
      int p = p0 + t;
      float x1 = 0.f, y1 = 0.f, x2 = 0.f, y2 = 0.f;
      if (p < P_NUM) {
        int a = p / HW, hw = p - a * HW;
        float2 c = ((const float2*)gridc)[b * HW + hw];
        float hx = anc[a * 2 + 0] * 0.5f, hy = anc[a * 2 + 1] * 0.5f;
        x1 = c.x - hx; y1 = c.y - hy; x2 = c.x + hx; y2 = c.y + hy;
      }
      sp4[t] = make_float4(x1, y1, x2, y2);
    }
    __syncthreads();
    const int nl = (t & 15) * 4;
    const int pi = t >> 4;
#pragma unroll
    for (int ip = 0; ip < 4; ip++) {
      const int pl = pi + 16 * ip;
      const int p = p0 + pl;
      const float4 pb = sp4[pl];
      const float spA = (pb.z - pb.x) * (pb.w - pb.y);
      float4 res;
#pragma unroll
      for (int jn = 0; jn < 4; jn++) {
        const int n = nl + jn;
        float bx1 = sb[n * 5 + 0], by1 = sb[n * 5 + 1];
        float bx2 = sb[n * 5 + 2], by2 = sb[n * 5 + 3];
        float s_b = (bx2 - bx1) * (by2 - by1);
        float ix1 = fmaxf(pb.x, bx1), iy1 = fmaxf(pb.y, by1);
        float ix2 = fminf(pb.z, bx2), iy2 = fminf(pb.w, by2);
        float si = fmaxf(ix2 - ix1, 0.f) * fmaxf(iy2 - iy1, 0.f);
        float su = spA + s_b - si;
        float iou = fmaxf(si / (su + 1e-8f), 0.f);
        bool invalid = (su <= 0.f) | (spA <= 0.f) | (s_b <= 0.f) | (bx1 < 0.f);
        float v = invalid ? 0.f : iou;
        if (jn == 0) res.x = v; else if (jn == 1) res.y = v;
        else if (jn == 2) res.z = v; else res.w = v;
      }
      if (p < P_NUM)
        *(float4*)&iou_out[((size_t)(b * P_NUM + p)) * 64 + nl] = res;
    }
    return;
  }

  // ===== GEMM: block 32m x 128n, 4 waves n-split (wave w: n w*32..+31) ======
  const int w = t >> 6, lane = t & 63;
  const int quad = lane >> 4, lo = lane & 15;
  const int b = bid / GEMM_MT;
  const int mt = bid - b * GEMM_MT;
  const int m0 = mt * 32;

  // stage roles: c_local = t>>3 (32 k-rows), mq = t&7 (8 x float4 = 32 m)
  const int cl = t >> 3;
  const int mq = t & 7;
  const int mld = min(m0 + 4 * mq, HW - 4);   // clamp tail (dup rows, guarded)
  const float* Fb = F + ((size_t)b * CIN + cl) * HW + mld;

  f32x4 acc[2][2];
#pragma unroll
  for (int i = 0; i < 2; i++)
#pragma unroll
    for (int j = 0; j < 2; j++) acc[i][j] = (f32x4){0.f, 0.f, 0.f, 0.f};

  float4 rg[3];       // F reg prefetch depth 3
  uint4 vb[3][2];     // B frag prefetch depth 3

  auto loadF = [&](int kk, float4* r) {
    *r = *(const float4*)(Fb + (size_t)kk * 32 * HW);
  };
  auto loadB = [&](int kk, uint4* v) {
    const uint4* p = W1f + (size_t)kk * 512 + 2 * w * 64 + lane;
    v[0] = p[0];
    v[1] = p[64];
  };
  auto stage = [&](int buf, const float4& r) {
    float* d = &sh.g.As[buf][(4 * mq) * ASTR3 + cl];
    d[0] = r.x; d[ASTR3] = r.y; d[2 * ASTR3] = r.z; d[3 * ASTR3] = r.w;
  };
  auto compute = [&](int buf, uint4* v) {
    const float* Ab = &sh.g.As[buf][lo * ASTR3 + quad * 8];
#pragma unroll
    for (int i = 0; i < 2; i++) {
      f32x4 a0 = *(const f32x4*)(Ab + i * 16 * ASTR3);
      f32x4 a1 = *(const f32x4*)(Ab + i * 16 * ASTR3 + 4);
      uint4 ap;
      ap.x = pack_bf16(a0[0], a0[1]);
      ap.y = pack_bf16(a0[2], a0[3]);
      ap.z = pack_bf16(a1[0], a1[1]);
      ap.w = pack_bf16(a1[2], a1[3]);
      bf16x8 af = __builtin_bit_cast(bf16x8, ap);
#pragma unroll
      for (int nf = 0; nf < 2; nf++)
        acc[i][nf] = __builtin_amdgcn_mfma_f32_16x16x32_bf16(
            af, __builtin_bit_cast(bf16x8, v[nf]), acc[i][nf], 0, 0, 0);
    }
  };

  loadF(0, &rg[0]); loadF(1, &rg[1]);
  loadB(0, vb[0]); loadB(1, vb[1]);
  stage(0, rg[0]);
  __syncthreads();
#pragma unroll
  for (int kk = 0; kk < KS_ALL; kk++) {
    const int cur = kk & 1;
    if (kk + 2 < KS_ALL) {
      loadF(kk + 2, &rg[(kk + 2) % 3]);
      loadB(kk + 2, vb[(kk + 2) % 3]);
    }
    compute(cur, vb[kk % 3]);
    if (kk + 1 < KS_ALL) stage(cur ^ 1, rg[(kk + 1) % 3]);
    __syncthreads();
  }

  // ---- epilogue: h = leakyrelu(acc + b1) -> bf16 h tile (wave-own n slice) -
#pragma unroll
  for (int i = 0; i < 2; i++) {
#pragma unroll
    for (int nf = 0; nf < 2; nf++) {
      const int n = w * 32 + nf * 16 + lo;
      const float bb = b1[n];
#pragma unroll
      for (int r = 0; r < 4; r++) {
        float v = acc[i][nf][r] + bb;
        v = v > 0.f ? v : 0.01f * v;
        unsigned u = __builtin_bit_cast(unsigned, v);
        sh.g.h[(i * 16 + quad * 4 + r) * HSTR2 + n] =
            (unsigned short)((u + 0x8000u) >> 16);
      }
    }
  }
  __syncthreads();

  // ---- W2 head: 10 units (mf,nt) split across 4 waves ----------------------
  for (int id = w; id < 10; id += 4) {
    const int mf = id / 5, nt = id - (id / 5) * 5;
    f32x4 acc2 = (f32x4){0.f, 0.f, 0.f, 0.f};
#pragma unroll
    for (int k2 = 0; k2 < 4; k2++) {
      bf16x8 haf = *(const bf16x8*)&sh.g.h[(mf * 16 + lo) * HSTR2 + k2 * 32 + quad * 8];
      bf16x8 bf = __builtin_bit_cast(bf16x8, W2f[(k2 * 5 + nt) * 64 + lane]);
      acc2 = __builtin_amdgcn_mfma_f32_16x16x32_bf16(haf, bf, acc2, 0, 0, 0);
    }
    const int o = nt * 16 + lo;
    if (o < 5 * A_NUM + C_NUM) {
      const float bz = b2[o];
      const int t5 = (o < 5 * A_NUM) ? (o % 5) : 5;
      const int mrow = m0 + mf * 16 + quad * 4;
#pragma unroll
      for (int r = 0; r < 4; r++) {
        const int m = mrow + r;
        if (m < HW) {
          float v = acc2[r] + bz;
          if (t5 == 0) v = 1.f / (1.f + expf(-v));
          else if (t5 == 1 || t5 == 2) v = 1.f / (1.f + expf(-v)) - 0.5f;
          Hd[((size_t)b * HW + m) * OSTR + o] = v;
        }
      }
    }
  }
}

// ---- gather: pure row copy from activated Hd -------------------------------
__global__ __launch_bounds__(256) void gather2(
    const int* __restrict__ pos_idx, const int* __restrict__ neg_idx,
    const float* __restrict__ Hd, float* __restrict__ out) {
  const int bid = blockIdx.x;
  if (bid < M_IDX / 8) {            // 512 blocks: 8 pos indices each
    const int g = threadIdx.x >> 5; // 32 lanes per index
    const int l = threadIdx.x & 31;
    const int slot = bid * 8 + g;
    const int idx = pos_idx[slot];
    const int b = idx / P_NUM, r = idx - b * P_NUM;
    const int a = r / HW, hw = r - a * HW;
    const float* row = Hd + ((size_t)b * HW + hw) * OSTR;
    if (l == 0)       out[CONF_OFF + slot] = row[a * 5];
    else if (l < 5)   out[OFFS_OFF + slot * 4 + (l - 1)] = row[a * 5 + l];
    else if (l < 25)  out[CLS_OFF + slot * C_NUM + (l - 5)] = row[5 * A_NUM + (l - 5)];
  } else {                          // 16 blocks: 1 neg index per thread
    const int tt = (bid - M_IDX / 8) * 256 + threadIdx.x;
    if (tt < M_IDX) {
      const int idx = neg_idx[tt];
      const int b = idx / P_NUM, r = idx - b * P_NUM;
      const int a = r / HW, hw = r - a * HW;
      out[CONF_OFF + M_IDX + tt] = Hd[((size_t)b * HW + hw) * OSTR + a * 5];
    }
  }
}

extern "C" void kernel_launch(void* const* d_in, const int* in_sizes, int n_in,
                              void* d_out, int out_size, void* d_ws, size_t ws_size,
                              hipStream_t stream) {
  const float* features = (const float*)d_in[0];
  const float* gridc    = (const float*)d_in[1];
  const float* anc      = (const float*)d_in[2];
  const float* bboxes   = (const float*)d_in[3];
  const int*   pos_idx  = (const int*)d_in[4];
  const int*   neg_idx  = (const int*)d_in[5];
  const float* W1       = (const float*)d_in[6];
  const float* b1       = (const float*)d_in[7];
  const float* W2       = (const float*)d_in[8];
  const float* b2       = (const float*)d_in[9];
  float* out = (float*)d_out;

  // ws: W1f (327680 B) | W2f (20480 B) | Hd (B*HW*OSTR fp32 = 8 MB)
  uint4* W1f = (uint4*)d_ws;
  uint4* W2f = (uint4*)((char*)d_ws + 327680);
  float* Hd  = (float*)((char*)d_ws + 327680 + 20480);

  hipLaunchKernelGGL(prep_w, dim3(85), dim3(256), 0, stream, W1, W2, W1f, W2f);
  hipLaunchKernelGGL(fused_main, dim3(GEMM_BLKS + IOU_BLKS), dim3(256), 0, stream,
                     features, W1f, W2f, b1, b2, Hd,
                     gridc, anc, bboxes, out + IOU_OFF);
  hipLaunchKernelGGL(gather2, dim3(M_IDX / 8 + 16), dim3(256), 0, stream,
                     pos_idx, neg_idx, Hd, out);
}

// Round 7
// 242.963 us; speedup vs baseline: 1.0729x; 1.0016x over previous
//
#include <hip/hip_runtime.h>
#include <cstdint>

#define A_NUM 9
#define C_NUM 20
#define B_SZ 32
#define HW 784            // 28*28
#define P_NUM (A_NUM*HW)  // 7056
#define NBOX 64
#define CIN 1280
#define HID 128
#define M_IDX 4096
#define NSTEP 10          // K-steps of BK=128 (10*128 = 1280)
#define HSTR2 136         // h LDS row stride in bf16 elems (272 B, 16B-aligned)
#define OSTR 80           // Hd row stride in floats (65 used, pad to 80)
#define IOU_PB 64         // p-rows per iou block

// output layout (flat concat in return order)
#define CONF_OFF 0
#define OFFS_OFF (2*M_IDX)                 // 8192
#define CLS_OFF  (OFFS_OFF + 4*M_IDX)      // 24576
#define IOU_OFF  (CLS_OFF + C_NUM*M_IDX)   // 106496

// fused grid: GEMM blocks first, IoU appended
#define GEMM_MT 25                                // 32-row m-tiles (800 >= 784)
#define GEMM_BLKS (GEMM_MT*B_SZ)                  // 800
#define IOU_BX ((P_NUM + IOU_PB - 1)/IOU_PB)      // 111
#define IOU_BLKS (IOU_BX*B_SZ)                    // 3552

typedef short bf16x8 __attribute__((ext_vector_type(8)));
typedef float f32x4  __attribute__((ext_vector_type(4)));
typedef unsigned u32x2 __attribute__((ext_vector_type(2)));

// round-half-up fp32->bf16, packed pair into one dword
__device__ __forceinline__ unsigned pack_bf16(float lo, float hi) {
  unsigned a = __builtin_bit_cast(unsigned, lo);
  unsigned b = __builtin_bit_cast(unsigned, hi);
  return ((a + 0x8000u) >> 16) | ((b + 0x8000u) & 0xffff0000u);
}

// lgkm-drain + raw barrier: LDS writes visible, global prefetch stays in flight
__device__ __forceinline__ void lds_barrier() {
  asm volatile("s_waitcnt lgkmcnt(0)" ::: "memory");
  __builtin_amdgcn_sched_barrier(0);
  __builtin_amdgcn_s_barrier();
  __builtin_amdgcn_sched_barrier(0);
}

// ---- weight prep: W1 and W2 fp32 -> bf16 MFMA B-fragment order -------------
// W1f layout: [ks(40)][ntile(8)][lane(64)][k8], lane=(quad,lo): n=ntile*16+lo,
// k = ks*32 + quad*8 + j.
// W2f layout: [ks(4)][ntile(5)][lane(64)][k8], n(=o)=ntile*16+lo (o>=65 -> 0).
__global__ __launch_bounds__(256) void prep_w(const float* __restrict__ W1,
                                              const float* __restrict__ W2,
                                              uint4* __restrict__ W1f,
                                              uint4* __restrict__ W2f) {
  int id = blockIdx.x * 256 + threadIdx.x;  // 85*256 = 21760 threads
  if (id < 20480) {
    int lane = id & 63;
    int ntile = (id >> 6) & 7;
    int ks = id >> 9;                       // 0..39
    int lo = lane & 15, quad = lane >> 4;
    int n = ntile * 16 + lo;
    int k0 = ks * 32 + quad * 8;
    const float* src = W1 + n * CIN + k0;
    float4 x = *(const float4*)src;
    float4 y = *(const float4*)(src + 4);
    uint4 p;
    p.x = pack_bf16(x.x, x.y);
    p.y = pack_bf16(x.z, x.w);
    p.z = pack_bf16(y.x, y.y);
    p.w = pack_bf16(y.z, y.w);
    W1f[id] = p;
  } else {
    int i2 = id - 20480;                    // 0..1279
    int lane = i2 & 63;
    int ntile = (i2 >> 6) % 5;
    int ks = i2 / 320;                      // 0..3
    int lo = lane & 15, quad = lane >> 4;
    int n = ntile * 16 + lo;
    int k0 = ks * 32 + quad * 8;
    uint4 p = (uint4){0, 0, 0, 0};
    if (n < 5 * A_NUM + C_NUM) {
      const float* src = W2 + n * HID + k0;
      float4 x = *(const float4*)src;
      float4 y = *(const float4*)(src + 4);
      p.x = pack_bf16(x.x, x.y);
      p.y = pack_bf16(x.z, x.w);
      p.z = pack_bf16(y.x, y.y);
      p.w = pack_bf16(y.z, y.w);
    }
    W2f[i2] = p;
  }
}

// ---- fused: BK=128 dbuf GEMM (raw-barrier pipeline) + head + IoU -----------
// A LDS tile (per buf): dwords, each = bf16 pair (k,k+1) for one m.
// off(m,kp) = m*64 + (((kp>>2) ^ (m&15))<<2) + (kp&3)   [XOR unit swizzle]
union SharedU {
  struct {
    unsigned Ab[2][32 * 64];             // 2 x 8192 B A tiles
    unsigned short h[32 * HSTR2];        // 8704 B bf16 h tile
  } g;                                   // 25088 B
  struct { float sb[NBOX * 5]; float4 sp4[IOU_PB]; } i;  // 2304 B (iou)
};

__global__ __launch_bounds__(256) void fused_main(
    const float* __restrict__ F, const uint4* __restrict__ W1f,
    const uint4* __restrict__ W2f, const float* __restrict__ b1,
    const float* __restrict__ b2, float* __restrict__ Hd,
    const float* __restrict__ gridc, const float* __restrict__ anc,
    const float* __restrict__ bboxes, float* __restrict__ iou_out) {
  __shared__ SharedU sh;
  const int bid = blockIdx.x;
  const int t = threadIdx.x;

  if (bid >= GEMM_BLKS) {
    // ================= IoU part (unchanged math) =================
    const int bid2 = bid - GEMM_BLKS;
    const int b = bid2 / IOU_BX;
    const int p0 = (bid2 - b * IOU_BX) * IOU_PB;
    float* sb = sh.i.sb;
    float4* sp4 = sh.i.sp4;
    for (int i = t; i < NBOX * 5; i += 256) sb[i] = bboxes[b * NBOX * 5 + i];
    if (t < IOU_PB) {
      int p = p0 + t;
      float x1 = 0.f, y1 = 0.f, x2 = 0.f, y2 = 0.f;
      if (p < P_NUM) {
        int a = p / HW, hw = p - a * HW;
        float2 c = ((const float2*)gridc)[b * HW + hw];
        float hx = anc[a * 2 + 0] * 0.5f, hy = anc[a * 2 + 1] * 0.5f;
        x1 = c.x - hx; y1 = c.y - hy; x2 = c.x + hx; y2 = c.y + hy;
      }
      sp4[t] = make_float4(x1, y1, x2, y2);
    }
    __syncthreads();
    const int nl = (t & 15) * 4;
    const int pi = t >> 4;
#pragma unroll
    for (int ip = 0; ip < 4; ip++) {
      const int pl = pi + 16 * ip;
      const int p = p0 + pl;
      const float4 pb = sp4[pl];
      const float spA = (pb.z - pb.x) * (pb.w - pb.y);
      float4 res;
#pragma unroll
      for (int jn = 0; jn < 4; jn++) {
        const int n = nl + jn;
        float bx1 = sb[n * 5 + 0], by1 = sb[n * 5 + 1];
        float bx2 = sb[n * 5 + 2], by2 = sb[n * 5 + 3];
        float s_b = (bx2 - bx1) * (by2 - by1);
        float ix1 = fmaxf(pb.x, bx1), iy1 = fmaxf(pb.y, by1);
        float ix2 = fminf(pb.z, bx2), iy2 = fminf(pb.w, by2);
        float si = fmaxf(ix2 - ix1, 0.f) * fmaxf(iy2 - iy1, 0.f);
        float su = spA + s_b - si;
        float iou = fmaxf(si / (su + 1e-8f), 0.f);
        bool invalid = (su <= 0.f) | (spA <= 0.f) | (s_b <= 0.f) | (bx1 < 0.f);
        float v = invalid ? 0.f : iou;
        if (jn == 0) res.x = v; else if (jn == 1) res.y = v;
        else if (jn == 2) res.z = v; else res.w = v;
      }
      if (p < P_NUM)
        *(float4*)&iou_out[((size_t)(b * P_NUM + p)) * 64 + nl] = res;
    }
    return;
  }

  // ===== GEMM: block 32m x 128n, 4 waves n-split, 10 steps of BK=128 ========
  const int w = t >> 6, lane = t & 63;
  const int quad = lane >> 4, lo = lane & 15;
  const int b = bid / GEMM_MT;
  const int mt = bid - b * GEMM_MT;
  const int m0 = mt * 32;

  // stage roles: m4 = t&7 (4-m group), kq = t>>3 (0..31: k rows 4kq..4kq+3)
  const int m4 = t & 7;
  const int kq = t >> 3;
  const int mld = min(m0 + 4 * m4, HW - 4);   // clamp tail (dup rows, guarded)
  const float* Fb = F + ((size_t)b * CIN + 4 * kq) * HW + mld;

  f32x4 acc[2][2];
#pragma unroll
  for (int i = 0; i < 2; i++)
#pragma unroll
    for (int j = 0; j < 2; j++) acc[i][j] = (f32x4){0.f, 0.f, 0.f, 0.f};

  f32x4 ra0[4], ra1[4];   // A prefetch: two sets of 4 k-rows x 4 m
  uint4 vb[8];            // B frags for current step [j(4) x nf(2)]

  auto loadA = [&](int s, f32x4* ra) {
    const float* p = Fb + (size_t)s * 128 * HW;
    ra[0] = *(const f32x4*)p;
    ra[1] = *(const f32x4*)(p + HW);
    ra[2] = *(const f32x4*)(p + 2 * HW);
    ra[3] = *(const f32x4*)(p + 3 * HW);
  };
  auto loadB = [&](int s) {
    const uint4* p = W1f + (size_t)(4 * s) * 512 + 2 * w * 64 + lane;
#pragma unroll
    for (int j = 0; j < 4; j++) {
      vb[2 * j]     = p[(size_t)j * 512];
      vb[2 * j + 1] = p[(size_t)j * 512 + 64];
    }
  };
  // pack k-pairs -> swizzled b64 writes
  auto stage = [&](unsigned* buf, const f32x4* ra) {
#pragma unroll
    for (int r = 0; r < 4; r++) {
      const int m = 4 * m4 + r;
      unsigned d0 = pack_bf16(ra[0][r], ra[1][r]);
      unsigned d1 = pack_bf16(ra[2][r], ra[3][r]);
      const int off = m * 64 + (((kq >> 1) ^ (m & 15)) << 2) + 2 * (kq & 1);
      *(u32x2*)(buf + off) = (u32x2){d0, d1};
    }
  };
  auto compute = [&](const unsigned* buf) {
#pragma unroll
    for (int j = 0; j < 4; j++) {
      const int u0 = ((j * 4 + quad) ^ lo) << 2;
      bf16x8 a0 = *(const bf16x8*)(buf + lo * 64 + u0);
      bf16x8 a1 = *(const bf16x8*)(buf + (lo + 16) * 64 + u0);
      acc[0][0] = __builtin_amdgcn_mfma_f32_16x16x32_bf16(
          a0, __builtin_bit_cast(bf16x8, vb[2 * j]), acc[0][0], 0, 0, 0);
      acc[0][1] = __builtin_amdgcn_mfma_f32_16x16x32_bf16(
          a0, __builtin_bit_cast(bf16x8, vb[2 * j + 1]), acc[0][1], 0, 0, 0);
      acc[1][0] = __builtin_amdgcn_mfma_f32_16x16x32_bf16(
          a1, __builtin_bit_cast(bf16x8, vb[2 * j]), acc[1][0], 0, 0, 0);
      acc[1][1] = __builtin_amdgcn_mfma_f32_16x16x32_bf16(
          a1, __builtin_bit_cast(bf16x8, vb[2 * j + 1]), acc[1][1], 0, 0, 0);
    }
  };

  loadA(0, ra0);
  loadA(1, ra1);
  stage(sh.g.Ab[0], ra0);
  lds_barrier();
#pragma unroll
  for (int s = 0; s < NSTEP; s++) {
    f32x4* raN = (s & 1) ? ra1 : ra0;   // refill (its data was staged last step)
    f32x4* raS = (s & 1) ? ra0 : ra1;   // holds A(s+1), stage now
    unsigned* bufC = sh.g.Ab[s & 1];
    unsigned* bufN = sh.g.Ab[(s & 1) ^ 1];
    if (s + 2 < NSTEP) loadA(s + 2, raN);
    loadB(s);
    if (s + 1 < NSTEP) stage(bufN, raS);
    compute(bufC);
    lds_barrier();
  }

  // ---- epilogue: h = leakyrelu(acc + b1) -> bf16 h tile (wave-own n slice) -
#pragma unroll
  for (int i = 0; i < 2; i++) {
#pragma unroll
    for (int nf = 0; nf < 2; nf++) {
      const int n = w * 32 + nf * 16 + lo;
      const float bb = b1[n];
#pragma unroll
      for (int r = 0; r < 4; r++) {
        float v = acc[i][nf][r] + bb;
        v = v > 0.f ? v : 0.01f * v;
        unsigned u = __builtin_bit_cast(unsigned, v);
        sh.g.h[(i * 16 + quad * 4 + r) * HSTR2 + n] =
            (unsigned short)((u + 0x8000u) >> 16);
      }
    }
  }
  __syncthreads();

  // ---- W2 head: 10 units (mf,nt) split across 4 waves ----------------------
  for (int id = w; id < 10; id += 4) {
    const int mf = id / 5, nt = id - (id / 5) * 5;
    f32x4 acc2 = (f32x4){0.f, 0.f, 0.f, 0.f};
#pragma unroll
    for (int k2 = 0; k2 < 4; k2++) {
      bf16x8 haf = *(const bf16x8*)&sh.g.h[(mf * 16 + lo) * HSTR2 + k2 * 32 + quad * 8];
      bf16x8 bf = __builtin_bit_cast(bf16x8, W2f[(k2 * 5 + nt) * 64 + lane]);
      acc2 = __builtin_amdgcn_mfma_f32_16x16x32_bf16(haf, bf, acc2, 0, 0, 0);
    }
    const int o = nt * 16 + lo;
    if (o < 5 * A_NUM + C_NUM) {
      const float bz = b2[o];
      const int t5 = (o < 5 * A_NUM) ? (o % 5) : 5;
      const int mrow = m0 + mf * 16 + quad * 4;
#pragma unroll
      for (int r = 0; r < 4; r++) {
        const int m = mrow + r;
        if (m < HW) {
          float v = acc2[r] + bz;
          if (t5 == 0) v = 1.f / (1.f + expf(-v));
          else if (t5 == 1 || t5 == 2) v = 1.f / (1.f + expf(-v)) - 0.5f;
          Hd[((size_t)b * HW + m) * OSTR + o] = v;
        }
      }
    }
  }
}

// ---- gather: pure row copy from activated Hd -------------------------------
__global__ __launch_bounds__(256) void gather2(
    const int* __restrict__ pos_idx, const int* __restrict__ neg_idx,
    const float* __restrict__ Hd, float* __restrict__ out) {
  const int bid = blockIdx.x;
  if (bid < M_IDX / 8) {            // 512 blocks: 8 pos indices each
    const int g = threadIdx.x >> 5; // 32 lanes per index
    const int l = threadIdx.x & 31;
    const int slot = bid * 8 + g;
    const int idx = pos_idx[slot];
    const int b = idx / P_NUM, r = idx - b * P_NUM;
    const int a = r / HW, hw = r - a * HW;
    const float* row = Hd + ((size_t)b * HW + hw) * OSTR;
    if (l == 0)       out[CONF_OFF + slot] = row[a * 5];
    else if (l < 5)   out[OFFS_OFF + slot * 4 + (l - 1)] = row[a * 5 + l];
    else if (l < 25)  out[CLS_OFF + slot * C_NUM + (l - 5)] = row[5 * A_NUM + (l - 5)];
  } else {                          // 16 blocks: 1 neg index per thread
    const int tt = (bid - M_IDX / 8) * 256 + threadIdx.x;
    if (tt < M_IDX) {
      const int idx = neg_idx[tt];
      const int b = idx / P_NUM, r = idx - b * P_NUM;
      const int a = r / HW, hw = r - a * HW;
      out[CONF_OFF + M_IDX + tt] = Hd[((size_t)b * HW + hw) * OSTR + a * 5];
    }
  }
}

extern "C" void kernel_launch(void* const* d_in, const int* in_sizes, int n_in,
                              void* d_out, int out_size, void* d_ws, size_t ws_size,
                              hipStream_t stream) {
  const float* features = (const float*)d_in[0];
  const float* gridc    = (const float*)d_in[1];
  const float* anc      = (const float*)d_in[2];
  const float* bboxes   = (const float*)d_in[3];
  const int*   pos_idx  = (const int*)d_in[4];
  const int*   neg_idx  = (const int*)d_in[5];
  const float* W1       = (const float*)d_in[6];
  const float* b1       = (const float*)d_in[7];
  const float* W2       = (const float*)d_in[8];
  const float* b2       = (const float*)d_in[9];
  float* out = (float*)d_out;

  // ws: W1f (327680 B) | W2f (20480 B) | Hd (B*HW*OSTR fp32 = 8 MB)
  uint4* W1f = (uint4*)d_ws;
  uint4* W2f = (uint4*)((char*)d_ws + 327680);
  float* Hd  = (float*)((char*)d_ws + 327680 + 20480);

  hipLaunchKernelGGL(prep_w, dim3(85), dim3(256), 0, stream, W1, W2, W1f, W2f);
  hipLaunchKernelGGL(fused_main, dim3(GEMM_BLKS + IOU_BLKS), dim3(256), 0, stream,
                     features, W1f, W2f, b1, b2, Hd,
                     gridc, anc, bboxes, out + IOU_OFF);
  hipLaunchKernelGGL(gather2, dim3(M_IDX / 8 + 16), dim3(256), 0, stream,
                     pos_idx, neg_idx, Hd, out);
}